// Round 1
// baseline (2419.442 us; speedup 1.0000x reference)
//
#include <hip/hip_runtime.h>
#include <cstdint>
#include <cstddef>

namespace {

constexpr int T = 10;
constexpr int N = 50000;
constexpr int R = 50000;
constexpr int DIN = 128;
constexpr int D = 64;
constexpr int E = 400000;

// ---------------------------------------------------------------- init
__global__ __launch_bounds__(256) void k_init(float* deg, int* cnt) {
  int i = blockIdx.x * 256 + threadIdx.x;
  if (i < T * N) { deg[i] = 1.0f; cnt[i] = 0; }  // deg starts at 1.0 = self-loop weight
}

// degree accumulate + dst histogram (counting sort pass 1)
__global__ __launch_bounds__(256) void k_edge_count(const int* __restrict__ ei,
                                                    const float* __restrict__ ew,
                                                    float* __restrict__ deg,
                                                    int* __restrict__ cnt) {
  int i = blockIdx.x * 256 + threadIdx.x;
  if (i >= T * E) return;
  int t = i / E, e = i - t * E;
  int dst = ei[(size_t)t * 2 * E + E + e];
  atomicAdd(&deg[t * N + dst], ew[(size_t)t * E + e]);
  atomicAdd(&cnt[t * N + dst], 1);
}

__global__ __launch_bounds__(256) void k_dinv(float* deg) {
  int i = blockIdx.x * 256 + threadIdx.x;
  if (i < T * N) { float d = deg[i]; deg[i] = d > 0.f ? 1.0f / sqrtf(d) : 0.f; }
}

// per-t exclusive scan of cnt -> rowptr, cursor (one block per t)
__global__ __launch_bounds__(256) void k_scan(const int* __restrict__ cnt,
                                              int* __restrict__ rowptr,
                                              int* __restrict__ cursor) {
  int t = blockIdx.x;
  int lane = threadIdx.x & 63, wid = threadIdx.x >> 6;
  __shared__ int wsum[4];
  __shared__ int carry_s;
  if (threadIdx.x == 0) carry_s = 0;
  __syncthreads();
  for (int base = 0; base < N; base += 256) {
    int i = base + threadIdx.x;
    int v = (i < N) ? cnt[t * N + i] : 0;
    int s = v;
    #pragma unroll
    for (int off = 1; off < 64; off <<= 1) {
      int u = __shfl_up(s, off, 64);
      if (lane >= off) s += u;
    }
    if (lane == 63) wsum[wid] = s;
    int carry = carry_s;
    __syncthreads();
    int wadd = 0;
    #pragma unroll
    for (int w = 0; w < 4; ++w) if (w < wid) wadd += wsum[w];
    int excl = carry + wadd + s - v;
    if (i < N) { rowptr[t * N + i] = excl; cursor[t * N + i] = excl; }
    __syncthreads();
    if (threadIdx.x == 0) carry_s = carry + wsum[0] + wsum[1] + wsum[2] + wsum[3];
    __syncthreads();
  }
}

// counting sort pass 2: place edge ids by dst
__global__ __launch_bounds__(256) void k_fill(const int* __restrict__ ei,
                                              int* __restrict__ cursor,
                                              int* __restrict__ perm) {
  int i = blockIdx.x * 256 + threadIdx.x;
  if (i >= T * E) return;
  int t = i / E, e = i - t * E;
  int dst = ei[(size_t)t * 2 * E + E + e];
  int pos = atomicAdd(&cursor[t * N + dst], 1);
  perm[(size_t)t * E + pos] = e;
}

// ---------------------------------------------------------------- GEMM: C[M][64] = A[M][K] @ W[64][K]^T
template <int K, int ROWS>
__global__ __launch_bounds__(256) void k_gemm(const float* __restrict__ A,
                                              const float* __restrict__ W,
                                              float* __restrict__ C, int M) {
  constexpr int KP = K + 4;        // pad: lane stride = 4 banks -> 8 addr/bank over the 8-cy b128 floor (free)
  constexpr int RPW = ROWS / 4;
  __shared__ float Ws[64 * KP];
  __shared__ float As[ROWS * K];   // broadcast reads, no pad needed
  int tid = threadIdx.x;
  for (int i = tid; i < 64 * K / 4; i += 256) {
    int j = i / (K / 4);
    int k4 = i - j * (K / 4);
    float4 w4 = reinterpret_cast<const float4*>(W)[i];
    *reinterpret_cast<float4*>(&Ws[j * KP + k4 * 4]) = w4;
  }
  long long row0 = (long long)blockIdx.x * ROWS;
  for (int i = tid; i < ROWS * K / 4; i += 256) {
    int mrow = i / (K / 4);
    int k4 = i - mrow * (K / 4);
    long long rr = row0 + mrow;
    float4 a4 = make_float4(0.f, 0.f, 0.f, 0.f);
    if (rr < M) a4 = reinterpret_cast<const float4*>(A + (size_t)rr * K)[k4];
    *reinterpret_cast<float4*>(&As[mrow * K + k4 * 4]) = a4;
  }
  __syncthreads();
  int lane = tid & 63, wv = tid >> 6;
  float acc[RPW];
  #pragma unroll
  for (int i = 0; i < RPW; ++i) acc[i] = 0.f;
  for (int k4 = 0; k4 < K / 4; ++k4) {
    float4 wj = *reinterpret_cast<const float4*>(&Ws[lane * KP + k4 * 4]);
    #pragma unroll
    for (int i = 0; i < RPW; ++i) {
      float4 a4 = *reinterpret_cast<const float4*>(&As[(wv * RPW + i) * K + k4 * 4]);
      acc[i] = fmaf(a4.x, wj.x, acc[i]);
      acc[i] = fmaf(a4.y, wj.y, acc[i]);
      acc[i] = fmaf(a4.z, wj.z, acc[i]);
      acc[i] = fmaf(a4.w, wj.w, acc[i]);
    }
  }
  #pragma unroll
  for (int i = 0; i < RPW; ++i) {
    long long rr = row0 + wv * RPW + i;
    if (rr < M) C[(size_t)rr * 64 + lane] = acc[i];
  }
}

// ---------------------------------------------------------------- GCN aggregation (gather over CSR), +bias, ReLU
// one wave per (t,n); lanes = 64 feature dims. SCATTER: write into time_embeds layout via global_idx.
template <bool SCATTER>
__global__ __launch_bounds__(256) void k_gather(
    const float* __restrict__ hw, const int* __restrict__ ei,
    const float* __restrict__ ew, const float* __restrict__ dinv,
    const int* __restrict__ rowptr, const int* __restrict__ cnt,
    const int* __restrict__ perm, const float* __restrict__ bias,
    const int* __restrict__ gidx, float* __restrict__ outp) {
  int wv = threadIdx.x >> 6, lane = threadIdx.x & 63;
  long long wave = (long long)blockIdx.x * 4 + wv;
  if (wave >= (long long)T * N) return;
  int t = (int)(wave / N);
  int n = (int)(wave - (long long)t * N);
  const float* hwt = hw + (size_t)t * N * D;
  const int* srct = ei + (size_t)t * 2 * E;
  const float* ewt = ew + (size_t)t * E;
  const int* permt = perm + (size_t)t * E;
  const float* dinvt = dinv + (size_t)t * N;
  float dn = dinvt[n];
  int start = rowptr[t * N + n];
  int m = cnt[t * N + n];
  float acc = 0.f;
  for (int b = 0; b < m; b += 64) {
    int mm = min(64, m - b);
    int e = (lane < mm) ? permt[start + b + lane] : 0;
    int s = srct[e];
    float wgt = (lane < mm) ? ewt[e] * dinvt[s] : 0.f;
    for (int i = 0; i < mm; ++i) {
      int si = __shfl(s, i, 64);
      float nm = __shfl(wgt, i, 64);
      acc = fmaf(nm, hwt[(size_t)si * D + lane], acc);
    }
  }
  // acc held sum of dinv[src]*ew*hw[src]; multiply dinv[dst]; add self-loop (norm = dn*dn) and bias
  float val = fmaf(acc, dn, fmaf(dn * dn, hwt[(size_t)n * D + lane], bias[lane]));
  val = fmaxf(val, 0.f);
  if (SCATTER) {
    int rr = gidx[(size_t)t * R + n];
    outp[((size_t)rr * T + t) * D + lane] = val;   // time_embeds[r][t][d]
  } else {
    outp[((size_t)t * N + n) * D + lane] = val;
  }
}

// ---------------------------------------------------------------- transpose weights for coalesced per-lane access
__global__ __launch_bounds__(256) void k_wtrans(const float* __restrict__ inW,
                                                const float* __restrict__ outW,
                                                const float* __restrict__ fcW,
                                                float* __restrict__ WtI,
                                                float* __restrict__ WtO,
                                                float* __restrict__ WtF) {
  int i = blockIdx.x * 256 + threadIdx.x;
  if (i < 192 * 64) { int jo = i / 64, d = i - jo * 64; WtI[d * 192 + jo] = inW[i]; }
  if (i < 64 * 64) {
    int j = i / 64, d = i - j * 64;
    WtO[d * 64 + j] = outW[i];
    WtF[d * 64 + j] = fcW[i];
  }
}

// ---------------------------------------------------------------- fused attention tail
// one wave per r. global_idx is a permutation (R==N) => mask all-present, bias == 0.
// only t = T-1 feeds the output, so q/out_proj/LN1/fc/LN2 computed for t=9 only.
__global__ __launch_bounds__(256) void k_attn(
    const float* __restrict__ te, const float* __restrict__ WtI,
    const float* __restrict__ inB, const float* __restrict__ WtO,
    const float* __restrict__ outB, const float* __restrict__ WtF,
    const float* __restrict__ fcB, const float* __restrict__ w1,
    const float* __restrict__ w2, const float* __restrict__ w3,
    const float* __restrict__ w4, const float* __restrict__ g1,
    const float* __restrict__ b1, const float* __restrict__ g2,
    const float* __restrict__ b2, float* __restrict__ out) {
  __shared__ float xs[4][T][D];
  __shared__ float scr[4][D];
  int wv = threadIdx.x >> 6, lane = threadIdx.x & 63;
  int r = blockIdx.x * 4 + wv;
  const float* ter = te + (size_t)r * T * D;
  #pragma unroll
  for (int i = 0; i < T; ++i) xs[wv][i][lane] = ter[i * D + lane];
  __syncthreads();
  // k,v for all s; q only at t = T-1. lane = output dim j.
  float kk[T], vv[T];
  float q9 = inB[lane];
  #pragma unroll
  for (int s = 0; s < T; ++s) { kk[s] = inB[64 + lane]; vv[s] = inB[128 + lane]; }
  #pragma unroll 4
  for (int d = 0; d < D; ++d) {
    float wq = WtI[d * 192 + lane];          // coalesced 256B
    float wk = WtI[d * 192 + 64 + lane];
    float wvd = WtI[d * 192 + 128 + lane];
    q9 = fmaf(wq, xs[wv][T - 1][d], q9);
    #pragma unroll
    for (int s = 0; s < T; ++s) {
      float xv = xs[wv][s][d];               // LDS broadcast
      kk[s] = fmaf(wk, xv, kk[s]);
      vv[s] = fmaf(wvd, xv, vv[s]);
    }
  }
  // scores per head (head = lane>>4, HD = 16), reduce q9*k over 16-lane groups
  float sc[T];
  #pragma unroll
  for (int s = 0; s < T; ++s) {
    float p = q9 * kk[s];
    p += __shfl_xor(p, 8, 16);
    p += __shfl_xor(p, 4, 16);
    p += __shfl_xor(p, 2, 16);
    p += __shfl_xor(p, 1, 16);
    sc[s] = p * 0.25f;                       // 1/sqrt(16)
  }
  float mx = sc[0];
  #pragma unroll
  for (int s = 1; s < T; ++s) mx = fmaxf(mx, sc[s]);
  float ssum = 0.f;
  #pragma unroll
  for (int s = 0; s < T; ++s) { sc[s] = expf(sc[s] - mx); ssum += sc[s]; }
  float rinv = 1.0f / ssum;
  float ao = 0.f;
  #pragma unroll
  for (int s = 0; s < T; ++s) ao = fmaf(sc[s] * rinv, vv[s], ao);
  scr[wv][lane] = ao;
  __syncthreads();
  float o = outB[lane];
  #pragma unroll 8
  for (int d = 0; d < D; ++d) o = fmaf(WtO[d * 64 + lane], scr[wv][d], o);
  float pre = w1[(T - 1) * D + lane] * xs[wv][T - 1][lane] + w2[(T - 1) * D + lane] * o;
  // LN1 across the 64 lanes
  float s1 = pre;
  #pragma unroll
  for (int off = 32; off >= 1; off >>= 1) s1 += __shfl_xor(s1, off, 64);
  float mu = s1 * (1.0f / 64.0f);
  float dv = pre - mu;
  float s2 = dv * dv;
  #pragma unroll
  for (int off = 32; off >= 1; off >>= 1) s2 += __shfl_xor(s2, off, 64);
  float rstd = 1.0f / sqrtf(s2 * (1.0f / 64.0f) + 1e-5f);
  float fin = dv * rstd * g1[lane] + b1[lane];
  __syncthreads();
  scr[wv][lane] = fin;
  __syncthreads();
  float o2 = fcB[lane];
  #pragma unroll 8
  for (int d = 0; d < D; ++d) o2 = fmaf(WtF[d * 64 + lane], scr[wv][d], o2);
  float pre2 = w3[lane] * fin + w4[lane] * o2;
  float u1 = pre2;
  #pragma unroll
  for (int off = 32; off >= 1; off >>= 1) u1 += __shfl_xor(u1, off, 64);
  float mu2 = u1 * (1.0f / 64.0f);
  float dv2 = pre2 - mu2;
  float u2 = dv2 * dv2;
  #pragma unroll
  for (int off = 32; off >= 1; off >>= 1) u2 += __shfl_xor(u2, off, 64);
  float rstd2 = 1.0f / sqrtf(u2 * (1.0f / 64.0f) + 1e-5f);
  out[(size_t)r * D + lane] = dv2 * rstd2 * g2[lane] + b2[lane];
}

}  // namespace

extern "C" void kernel_launch(void* const* d_in, const int* in_sizes, int n_in,
                              void* d_out, int out_size, void* d_ws, size_t ws_size,
                              hipStream_t stream) {
  const float* x      = (const float*)d_in[0];
  const int*   ei     = (const int*)d_in[1];
  const float* ew     = (const float*)d_in[2];
  const int*   gidx   = (const int*)d_in[3];
  const float* gcn1_w = (const float*)d_in[4];
  const float* gcn1_b = (const float*)d_in[5];
  const float* gcn2_w = (const float*)d_in[6];
  const float* gcn2_b = (const float*)d_in[7];
  const float* in_w   = (const float*)d_in[8];
  const float* in_b   = (const float*)d_in[9];
  const float* out_w  = (const float*)d_in[10];
  const float* out_b  = (const float*)d_in[11];
  const float* w1     = (const float*)d_in[12];
  const float* w2     = (const float*)d_in[13];
  const float* w3     = (const float*)d_in[14];
  const float* w4     = (const float*)d_in[15];
  const float* ln1_g  = (const float*)d_in[16];
  const float* ln1_b  = (const float*)d_in[17];
  const float* ln2_g  = (const float*)d_in[18];
  const float* ln2_b  = (const float*)d_in[19];
  const float* fc_w   = (const float*)d_in[20];
  const float* fc_b   = (const float*)d_in[21];
  float* outp = (float*)d_out;

  // workspace layout (~281 MB total)
  char* ws = (char*)d_ws;
  size_t off = 0;
  auto alloc = [&](size_t bytes) {
    void* p = ws + off;
    off += (bytes + 255) & ~(size_t)255;
    return p;
  };
  float* deg    = (float*)alloc(sizeof(float) * T * N);            // deg -> dinv (in place)
  int*   cnt    = (int*)alloc(sizeof(int) * T * N);
  int*   rowptr = (int*)alloc(sizeof(int) * T * N);
  int*   cursor = (int*)alloc(sizeof(int) * T * N);
  int*   perm   = (int*)alloc(sizeof(int) * (size_t)T * E);
  float* hw     = (float*)alloc(sizeof(float) * (size_t)T * N * D); // hw1, then reused as hw2
  float* h1te   = (float*)alloc(sizeof(float) * (size_t)T * N * D); // h1, then reused as time_embeds
  float* WtI    = (float*)alloc(sizeof(float) * 64 * 192);
  float* WtO    = (float*)alloc(sizeof(float) * 64 * 64);
  float* WtF    = (float*)alloc(sizeof(float) * 64 * 64);

  const int M = T * N;
  k_init<<<(T * N + 255) / 256, 256, 0, stream>>>(deg, cnt);
  k_edge_count<<<(T * E + 255) / 256, 256, 0, stream>>>(ei, ew, deg, cnt);
  k_dinv<<<(T * N + 255) / 256, 256, 0, stream>>>(deg);
  k_scan<<<T, 256, 0, stream>>>(cnt, rowptr, cursor);
  k_fill<<<(T * E + 255) / 256, 256, 0, stream>>>(ei, cursor, perm);

  k_gemm<DIN, 32><<<(M + 31) / 32, 256, 0, stream>>>(x, gcn1_w, hw, M);
  k_gather<false><<<(M + 3) / 4, 256, 0, stream>>>(hw, ei, ew, deg, rowptr, cnt, perm,
                                                   gcn1_b, nullptr, h1te);
  k_gemm<D, 64><<<(M + 63) / 64, 256, 0, stream>>>(h1te, gcn2_w, hw, M);
  k_gather<true><<<(M + 3) / 4, 256, 0, stream>>>(hw, ei, ew, deg, rowptr, cnt, perm,
                                                  gcn2_b, gidx, h1te);  // writes time_embeds

  k_wtrans<<<48, 256, 0, stream>>>(in_w, out_w, fc_w, WtI, WtO, WtF);
  k_attn<<<R / 4, 256, 0, stream>>>(h1te, WtI, in_b, WtO, out_b, WtF, fc_b,
                                    w1, w2, w3, w4, ln1_g, ln1_b, ln2_g, ln2_b, outp);
}

// Round 2
// 2125.172 us; speedup vs baseline: 1.1385x; 1.1385x over previous
//
#include <hip/hip_runtime.h>
#include <cstdint>
#include <cstddef>

namespace {

constexpr int T = 10;
constexpr int N = 50000;
constexpr int R = 50000;
constexpr int DIN = 128;
constexpr int D = 64;
constexpr int E = 400000;

__device__ __forceinline__ float bf2f(unsigned short u) {
  return __uint_as_float(((unsigned)u) << 16);
}
__device__ __forceinline__ unsigned short f2bf(float f) {
  unsigned u = __float_as_uint(f);
  return (unsigned short)((u + 0x7FFFu + ((u >> 16) & 1u)) >> 16);
}

// ---------------------------------------------------------------- init
__global__ __launch_bounds__(256) void k_init(float* deg, int* cnt) {
  int i = blockIdx.x * 256 + threadIdx.x;
  if (i < T * N) { deg[i] = 1.0f; cnt[i] = 0; }  // deg starts at 1.0 = self-loop weight
}

// degree accumulate + dst histogram (counting sort pass 1)
__global__ __launch_bounds__(256) void k_edge_count(const int* __restrict__ ei,
                                                    const float* __restrict__ ew,
                                                    float* __restrict__ deg,
                                                    int* __restrict__ cnt) {
  int i = blockIdx.x * 256 + threadIdx.x;
  if (i >= T * E) return;
  int t = i / E, e = i - t * E;
  int dst = ei[(size_t)t * 2 * E + E + e];
  atomicAdd(&deg[t * N + dst], ew[(size_t)t * E + e]);
  atomicAdd(&cnt[t * N + dst], 1);
}

__global__ __launch_bounds__(256) void k_dinv(float* deg) {
  int i = blockIdx.x * 256 + threadIdx.x;
  if (i < T * N) { float d = deg[i]; deg[i] = d > 0.f ? 1.0f / sqrtf(d) : 0.f; }
}

// per-t exclusive scan of cnt -> rowptr, cursor (one block per t)
__global__ __launch_bounds__(256) void k_scan(const int* __restrict__ cnt,
                                              int* __restrict__ rowptr,
                                              int* __restrict__ cursor) {
  int t = blockIdx.x;
  int lane = threadIdx.x & 63, wid = threadIdx.x >> 6;
  __shared__ int wsum[4];
  __shared__ int carry_s;
  if (threadIdx.x == 0) carry_s = 0;
  __syncthreads();
  for (int base = 0; base < N; base += 256) {
    int i = base + threadIdx.x;
    int v = (i < N) ? cnt[t * N + i] : 0;
    int s = v;
    #pragma unroll
    for (int off = 1; off < 64; off <<= 1) {
      int u = __shfl_up(s, off, 64);
      if (lane >= off) s += u;
    }
    if (lane == 63) wsum[wid] = s;
    int carry = carry_s;
    __syncthreads();
    int wadd = 0;
    #pragma unroll
    for (int w = 0; w < 4; ++w) if (w < wid) wadd += wsum[w];
    int excl = carry + wadd + s - v;
    if (i < N) { rowptr[t * N + i] = excl; cursor[t * N + i] = excl; }
    __syncthreads();
    if (threadIdx.x == 0) carry_s = carry + wsum[0] + wsum[1] + wsum[2] + wsum[3];
    __syncthreads();
  }
}

// counting sort pass 2: place packed (src, ew*dinv[src]) records by dst
__global__ __launch_bounds__(256) void k_fill(const int* __restrict__ ei,
                                              const float* __restrict__ ew,
                                              const float* __restrict__ dinv,
                                              int* __restrict__ cursor,
                                              int2* __restrict__ pk) {
  int i = blockIdx.x * 256 + threadIdx.x;
  if (i >= T * E) return;
  int t = i / E, e = i - t * E;
  const int* eit = ei + (size_t)t * 2 * E;
  int src = eit[e];
  int dst = eit[E + e];
  float w = ew[(size_t)t * E + e] * dinv[t * N + src];  // dinv slice is L2-resident (200 KB)
  int pos = atomicAdd(&cursor[t * N + dst], 1);
  int2 rec;
  rec.x = src;
  rec.y = __float_as_int(w);
  pk[(size_t)t * E + pos] = rec;
}

// ---------------------------------------------------------------- GEMM: C[M][64] = A[M][K] @ W[64][K]^T, bf16 out
template <int K, int ROWS, bool ABF16>
__global__ __launch_bounds__(256) void k_gemm(const void* __restrict__ Av,
                                              const float* __restrict__ W,
                                              unsigned short* __restrict__ C, int M) {
  constexpr int KP = K + 4;
  constexpr int RPW = ROWS / 4;
  __shared__ float Ws[64 * KP];
  __shared__ float As[ROWS * K];   // read back as same-address broadcasts
  int tid = threadIdx.x;
  for (int i = tid; i < 64 * K / 4; i += 256) {
    int j = i / (K / 4);
    int k4 = i - j * (K / 4);
    float4 w4 = reinterpret_cast<const float4*>(W)[i];
    *reinterpret_cast<float4*>(&Ws[j * KP + k4 * 4]) = w4;
  }
  long long row0 = (long long)blockIdx.x * ROWS;
  for (int i = tid; i < ROWS * K / 4; i += 256) {
    int mrow = i / (K / 4);
    int k4 = i - mrow * (K / 4);
    long long rr = row0 + mrow;
    float4 a4 = make_float4(0.f, 0.f, 0.f, 0.f);
    if (rr < M) {
      if (ABF16) {
        ushort4 u = reinterpret_cast<const ushort4*>(
            (const unsigned short*)Av + (size_t)rr * K)[k4];
        a4 = make_float4(bf2f(u.x), bf2f(u.y), bf2f(u.z), bf2f(u.w));
      } else {
        a4 = reinterpret_cast<const float4*>((const float*)Av + (size_t)rr * K)[k4];
      }
    }
    *reinterpret_cast<float4*>(&As[mrow * K + k4 * 4]) = a4;
  }
  __syncthreads();
  int lane = tid & 63, wv = tid >> 6;
  float acc[RPW];
  #pragma unroll
  for (int i = 0; i < RPW; ++i) acc[i] = 0.f;
  #pragma unroll 4
  for (int k4 = 0; k4 < K / 4; ++k4) {
    float4 wj = *reinterpret_cast<const float4*>(&Ws[lane * KP + k4 * 4]);
    #pragma unroll
    for (int i = 0; i < RPW; ++i) {
      float4 a4 = *reinterpret_cast<const float4*>(&As[(wv * RPW + i) * K + k4 * 4]);
      acc[i] = fmaf(a4.x, wj.x, acc[i]);
      acc[i] = fmaf(a4.y, wj.y, acc[i]);
      acc[i] = fmaf(a4.z, wj.z, acc[i]);
      acc[i] = fmaf(a4.w, wj.w, acc[i]);
    }
  }
  #pragma unroll
  for (int i = 0; i < RPW; ++i) {
    long long rr = row0 + wv * RPW + i;
    if (rr < M) C[(size_t)rr * 64 + lane] = f2bf(acc[i]);
  }
}

// ---------------------------------------------------------------- GCN aggregation (gather over CSR), +bias, ReLU
// one wave per (t,n). Lanes form 4 groups of 16; group g handles edge 4i+g,
// each lane covers 4 dims via ushort4 bf16 loads (512 B / load instr over 4 edges).
template <bool SCATTER>
__global__ __launch_bounds__(256) void k_gather(
    const unsigned short* __restrict__ hw, const int2* __restrict__ pk,
    const float* __restrict__ dinv, const int* __restrict__ rowptr,
    const int* __restrict__ cnt, const float* __restrict__ bias,
    const int* __restrict__ gidx, unsigned short* __restrict__ outp) {
  int wv = threadIdx.x >> 6, lane = threadIdx.x & 63;
  long long wave = (long long)blockIdx.x * 4 + wv;
  if (wave >= (long long)T * N) return;
  int t = (int)(wave / N);
  int n = (int)(wave - (long long)t * N);
  const unsigned short* hwt = hw + (size_t)t * N * D;
  const int2* pkt = pk + (size_t)t * E;
  float dn = dinv[t * N + n];
  int start = rowptr[t * N + n];
  int m = cnt[t * N + n];
  int grp = lane >> 4, sub = lane & 15;
  float4 acc0 = make_float4(0.f, 0.f, 0.f, 0.f);
  float4 acc1 = make_float4(0.f, 0.f, 0.f, 0.f);
  for (int b = 0; b < m; b += 64) {
    int mm = min(64, m - b);
    int2 rec = make_int2(0, 0);                  // w = 0.0f for pad lanes
    if (lane < mm) rec = pkt[start + b + lane];
    int s_l = rec.x;
    float w_l = __int_as_float(rec.y);
    int iters = (mm + 3) >> 2;
    int i = 0;
    for (; i + 2 <= iters; i += 2) {
      int i0 = 4 * i + grp;
      int i1 = i0 + 4;
      int sa = __shfl(s_l, i0, 64);
      float wa = __shfl(w_l, i0, 64);
      int sb = __shfl(s_l, i1, 64);
      float wb = __shfl(w_l, i1, 64);
      ushort4 ha = *(const ushort4*)(hwt + (size_t)sa * D + (sub << 2));
      ushort4 hb = *(const ushort4*)(hwt + (size_t)sb * D + (sub << 2));
      acc0.x = fmaf(wa, bf2f(ha.x), acc0.x);
      acc0.y = fmaf(wa, bf2f(ha.y), acc0.y);
      acc0.z = fmaf(wa, bf2f(ha.z), acc0.z);
      acc0.w = fmaf(wa, bf2f(ha.w), acc0.w);
      acc1.x = fmaf(wb, bf2f(hb.x), acc1.x);
      acc1.y = fmaf(wb, bf2f(hb.y), acc1.y);
      acc1.z = fmaf(wb, bf2f(hb.z), acc1.z);
      acc1.w = fmaf(wb, bf2f(hb.w), acc1.w);
    }
    if (i < iters) {
      int i0 = 4 * i + grp;
      int sa = __shfl(s_l, i0, 64);
      float wa = __shfl(w_l, i0, 64);
      ushort4 ha = *(const ushort4*)(hwt + (size_t)sa * D + (sub << 2));
      acc0.x = fmaf(wa, bf2f(ha.x), acc0.x);
      acc0.y = fmaf(wa, bf2f(ha.y), acc0.y);
      acc0.z = fmaf(wa, bf2f(ha.z), acc0.z);
      acc0.w = fmaf(wa, bf2f(ha.w), acc0.w);
    }
  }
  acc0.x += acc1.x; acc0.y += acc1.y; acc0.z += acc1.z; acc0.w += acc1.w;
  // cross-group reduction (groups hold disjoint edge subsets of the same dst)
  acc0.x += __shfl_xor(acc0.x, 16, 64); acc0.x += __shfl_xor(acc0.x, 32, 64);
  acc0.y += __shfl_xor(acc0.y, 16, 64); acc0.y += __shfl_xor(acc0.y, 32, 64);
  acc0.z += __shfl_xor(acc0.z, 16, 64); acc0.z += __shfl_xor(acc0.z, 32, 64);
  acc0.w += __shfl_xor(acc0.w, 16, 64); acc0.w += __shfl_xor(acc0.w, 32, 64);
  if (grp == 0) {
    ushort4 sv = *(const ushort4*)(hwt + (size_t)n * D + (sub << 2));
    float4 b4 = *(const float4*)(bias + (sub << 2));
    float dnn = dn * dn;
    float vx = fmaxf(fmaf(acc0.x, dn, fmaf(dnn, bf2f(sv.x), b4.x)), 0.f);
    float vy = fmaxf(fmaf(acc0.y, dn, fmaf(dnn, bf2f(sv.y), b4.y)), 0.f);
    float vz = fmaxf(fmaf(acc0.z, dn, fmaf(dnn, bf2f(sv.z), b4.z)), 0.f);
    float vw = fmaxf(fmaf(acc0.w, dn, fmaf(dnn, bf2f(sv.w), b4.w)), 0.f);
    ushort4 o;
    o.x = f2bf(vx); o.y = f2bf(vy); o.z = f2bf(vz); o.w = f2bf(vw);
    size_t ro;
    if (SCATTER) {
      int rr = gidx[(size_t)t * R + n];
      ro = ((size_t)rr * T + t) * D;     // time_embeds[r][t][d]
    } else {
      ro = ((size_t)t * N + n) * D;
    }
    *(ushort4*)(outp + ro + (sub << 2)) = o;
  }
}

// ---------------------------------------------------------------- fused attention tail
// one wave per r. global_idx is a permutation (R==N) => mask all-present, bias == 0.
// only t = T-1 feeds the output. All LDS use is wave-private -> no barriers.
__global__ __launch_bounds__(256) void k_attn(
    const unsigned short* __restrict__ te, const float* __restrict__ inW,
    const float* __restrict__ inB, const float* __restrict__ outW,
    const float* __restrict__ outB, const float* __restrict__ fcW,
    const float* __restrict__ fcB, const float* __restrict__ w1,
    const float* __restrict__ w2, const float* __restrict__ w3,
    const float* __restrict__ w4, const float* __restrict__ g1,
    const float* __restrict__ b1, const float* __restrict__ g2,
    const float* __restrict__ b2, float* __restrict__ out) {
  __shared__ float xs[4][T][D];
  __shared__ float scr[4][D];
  int wv = threadIdx.x >> 6, lane = threadIdx.x & 63;
  int r = blockIdx.x * 4 + wv;
  const unsigned short* ter = te + (size_t)r * T * D;
  #pragma unroll
  for (int i = 0; i < 5; ++i) {                  // 640 bf16 via ushort2/lane
    ushort2 u2 = reinterpret_cast<const ushort2*>(ter)[i * 64 + lane];
    int row = 2 * i + (lane >> 5);
    int col = (2 * lane) & 63;
    float2 f2 = make_float2(bf2f(u2.x), bf2f(u2.y));
    *(float2*)&xs[wv][row][col] = f2;
  }
  // k,v for all s; q only at t = T-1. lane = output dim j. Weights read row-major
  // (per-lane rows, 16 KB L1-resident); x via same-address b128 LDS broadcasts.
  float kk[T], vv[T];
  float q9 = inB[lane];
  #pragma unroll
  for (int s = 0; s < T; ++s) { kk[s] = inB[64 + lane]; vv[s] = inB[128 + lane]; }
  const float4* wq4 = (const float4*)(inW + (size_t)lane * D);
  const float4* wk4 = (const float4*)(inW + ((size_t)lane + 64) * D);
  const float4* wv4 = (const float4*)(inW + ((size_t)lane + 128) * D);
  #pragma unroll 4
  for (int d4 = 0; d4 < D / 4; ++d4) {
    float4 wq = wq4[d4], wk = wk4[d4], wvd = wv4[d4];
    float4 xq = *(const float4*)&xs[wv][T - 1][d4 * 4];
    q9 = fmaf(wq.x, xq.x, q9); q9 = fmaf(wq.y, xq.y, q9);
    q9 = fmaf(wq.z, xq.z, q9); q9 = fmaf(wq.w, xq.w, q9);
    #pragma unroll
    for (int s = 0; s < T; ++s) {
      float4 xv = *(const float4*)&xs[wv][s][d4 * 4];
      kk[s] = fmaf(wk.x, xv.x, kk[s]); kk[s] = fmaf(wk.y, xv.y, kk[s]);
      kk[s] = fmaf(wk.z, xv.z, kk[s]); kk[s] = fmaf(wk.w, xv.w, kk[s]);
      vv[s] = fmaf(wvd.x, xv.x, vv[s]); vv[s] = fmaf(wvd.y, xv.y, vv[s]);
      vv[s] = fmaf(wvd.z, xv.z, vv[s]); vv[s] = fmaf(wvd.w, xv.w, vv[s]);
    }
  }
  // scores per head (head = lane>>4, HD = 16)
  float sc[T];
  #pragma unroll
  for (int s = 0; s < T; ++s) {
    float p = q9 * kk[s];
    p += __shfl_xor(p, 8, 16);
    p += __shfl_xor(p, 4, 16);
    p += __shfl_xor(p, 2, 16);
    p += __shfl_xor(p, 1, 16);
    sc[s] = p * 0.25f;                            // 1/sqrt(16)
  }
  float mx = sc[0];
  #pragma unroll
  for (int s = 1; s < T; ++s) mx = fmaxf(mx, sc[s]);
  float ssum = 0.f;
  #pragma unroll
  for (int s = 0; s < T; ++s) { sc[s] = expf(sc[s] - mx); ssum += sc[s]; }
  float rinv = 1.0f / ssum;
  float ao = 0.f;
  #pragma unroll
  for (int s = 0; s < T; ++s) ao = fmaf(sc[s] * rinv, vv[s], ao);
  scr[wv][lane] = ao;
  float o = outB[lane];
  #pragma unroll 4
  for (int d4 = 0; d4 < D / 4; ++d4) {
    float4 wo = *(const float4*)(outW + (size_t)lane * D + d4 * 4);
    float4 s4 = *(const float4*)&scr[wv][d4 * 4];
    o = fmaf(wo.x, s4.x, o); o = fmaf(wo.y, s4.y, o);
    o = fmaf(wo.z, s4.z, o); o = fmaf(wo.w, s4.w, o);
  }
  float pre = w1[(T - 1) * D + lane] * xs[wv][T - 1][lane] + w2[(T - 1) * D + lane] * o;
  // LN1 across the 64 lanes
  float s1 = pre;
  #pragma unroll
  for (int off = 32; off >= 1; off >>= 1) s1 += __shfl_xor(s1, off, 64);
  float mu = s1 * (1.0f / 64.0f);
  float dv = pre - mu;
  float s2 = dv * dv;
  #pragma unroll
  for (int off = 32; off >= 1; off >>= 1) s2 += __shfl_xor(s2, off, 64);
  float rstd = 1.0f / sqrtf(s2 * (1.0f / 64.0f) + 1e-5f);
  float fin = dv * rstd * g1[lane] + b1[lane];
  scr[wv][lane] = fin;
  float o2 = fcB[lane];
  #pragma unroll 4
  for (int d4 = 0; d4 < D / 4; ++d4) {
    float4 wf = *(const float4*)(fcW + (size_t)lane * D + d4 * 4);
    float4 s4 = *(const float4*)&scr[wv][d4 * 4];
    o2 = fmaf(wf.x, s4.x, o2); o2 = fmaf(wf.y, s4.y, o2);
    o2 = fmaf(wf.z, s4.z, o2); o2 = fmaf(wf.w, s4.w, o2);
  }
  float pre2 = w3[lane] * fin + w4[lane] * o2;
  float u1 = pre2;
  #pragma unroll
  for (int off = 32; off >= 1; off >>= 1) u1 += __shfl_xor(u1, off, 64);
  float mu2 = u1 * (1.0f / 64.0f);
  float dv2 = pre2 - mu2;
  float u2 = dv2 * dv2;
  #pragma unroll
  for (int off = 32; off >= 1; off >>= 1) u2 += __shfl_xor(u2, off, 64);
  float rstd2 = 1.0f / sqrtf(u2 * (1.0f / 64.0f) + 1e-5f);
  out[(size_t)r * D + lane] = dv2 * rstd2 * g2[lane] + b2[lane];
}

}  // namespace

extern "C" void kernel_launch(void* const* d_in, const int* in_sizes, int n_in,
                              void* d_out, int out_size, void* d_ws, size_t ws_size,
                              hipStream_t stream) {
  const float* x      = (const float*)d_in[0];
  const int*   ei     = (const int*)d_in[1];
  const float* ew     = (const float*)d_in[2];
  const int*   gidx   = (const int*)d_in[3];
  const float* gcn1_w = (const float*)d_in[4];
  const float* gcn1_b = (const float*)d_in[5];
  const float* gcn2_w = (const float*)d_in[6];
  const float* gcn2_b = (const float*)d_in[7];
  const float* in_w   = (const float*)d_in[8];
  const float* in_b   = (const float*)d_in[9];
  const float* out_w  = (const float*)d_in[10];
  const float* out_b  = (const float*)d_in[11];
  const float* w1     = (const float*)d_in[12];
  const float* w2     = (const float*)d_in[13];
  const float* w3     = (const float*)d_in[14];
  const float* w4     = (const float*)d_in[15];
  const float* ln1_g  = (const float*)d_in[16];
  const float* ln1_b  = (const float*)d_in[17];
  const float* ln2_g  = (const float*)d_in[18];
  const float* ln2_b  = (const float*)d_in[19];
  const float* fc_w   = (const float*)d_in[20];
  const float* fc_b   = (const float*)d_in[21];
  float* outp = (float*)d_out;

  char* ws = (char*)d_ws;
  size_t off = 0;
  auto alloc = [&](size_t bytes) {
    void* p = ws + off;
    off += (bytes + 255) & ~(size_t)255;
    return p;
  };
  float* deg    = (float*)alloc(sizeof(float) * T * N);               // deg -> dinv (in place)
  int*   cnt    = (int*)alloc(sizeof(int) * T * N);
  int*   rowptr = (int*)alloc(sizeof(int) * T * N);
  int*   cursor = (int*)alloc(sizeof(int) * T * N);
  int2*  pk     = (int2*)alloc(sizeof(int2) * (size_t)T * E);          // packed (src, ew*dinv[src])
  unsigned short* hw   = (unsigned short*)alloc(sizeof(short) * (size_t)T * N * D);  // bf16 hw1/hw2
  unsigned short* h1te = (unsigned short*)alloc(sizeof(short) * (size_t)T * N * D);  // bf16 h1 / time_embeds

  const int M = T * N;
  k_init<<<(T * N + 255) / 256, 256, 0, stream>>>(deg, cnt);
  k_edge_count<<<(T * E + 255) / 256, 256, 0, stream>>>(ei, ew, deg, cnt);
  k_dinv<<<(T * N + 255) / 256, 256, 0, stream>>>(deg);
  k_scan<<<T, 256, 0, stream>>>(cnt, rowptr, cursor);
  k_fill<<<(T * E + 255) / 256, 256, 0, stream>>>(ei, ew, deg, cursor, pk);

  k_gemm<DIN, 32, false><<<(M + 31) / 32, 256, 0, stream>>>(x, gcn1_w, hw, M);
  k_gather<false><<<(M + 3) / 4, 256, 0, stream>>>(hw, pk, deg, rowptr, cnt, gcn1_b,
                                                   nullptr, h1te);
  k_gemm<D, 64, true><<<(M + 63) / 64, 256, 0, stream>>>(h1te, gcn2_w, hw, M);
  k_gather<true><<<(M + 3) / 4, 256, 0, stream>>>(hw, pk, deg, rowptr, cnt, gcn2_b,
                                                  gidx, h1te);  // writes time_embeds (bf16)

  k_attn<<<R / 4, 256, 0, stream>>>(h1te, in_w, in_b, out_w, out_b, fc_w, fc_b,
                                    w1, w2, w3, w4, ln1_g, ln1_b, ln2_g, ln2_b, outp);
}

// Round 3
// 1685.186 us; speedup vs baseline: 1.4357x; 1.2611x over previous
//
#include <hip/hip_runtime.h>
#include <cstdint>
#include <cstddef>

namespace {

constexpr int T = 10;
constexpr int N = 50000;
constexpr int R = 50000;
constexpr int DIN = 128;
constexpr int D = 64;
constexpr int E = 400000;

typedef __attribute__((ext_vector_type(8))) short bf16x8;
typedef __attribute__((ext_vector_type(4))) float f32x4;

__device__ __forceinline__ float bf2f(unsigned short u) {
  return __uint_as_float(((unsigned)u) << 16);
}
__device__ __forceinline__ unsigned short f2bf(float f) {
  unsigned u = __float_as_uint(f);
  return (unsigned short)((u + 0x7FFFu + ((u >> 16) & 1u)) >> 16);
}

// ---------------------------------------------------------------- init
__global__ __launch_bounds__(256) void k_init(float* deg, int* cnt) {
  int i = blockIdx.x * 256 + threadIdx.x;
  if (i < T * N) { deg[i] = 1.0f; cnt[i] = 0; }  // deg starts at 1.0 = self-loop weight
}

__global__ __launch_bounds__(256) void k_edge_count(const int* __restrict__ ei,
                                                    const float* __restrict__ ew,
                                                    float* __restrict__ deg,
                                                    int* __restrict__ cnt) {
  int i = blockIdx.x * 256 + threadIdx.x;
  if (i >= T * E) return;
  int t = i / E, e = i - t * E;
  int dst = ei[(size_t)t * 2 * E + E + e];
  atomicAdd(&deg[t * N + dst], ew[(size_t)t * E + e]);
  atomicAdd(&cnt[t * N + dst], 1);
}

__global__ __launch_bounds__(256) void k_dinv(float* deg) {
  int i = blockIdx.x * 256 + threadIdx.x;
  if (i < T * N) { float d = deg[i]; deg[i] = d > 0.f ? 1.0f / sqrtf(d) : 0.f; }
}

// per-t exclusive scan of cnt -> rowptr, cursor (one block per t)
__global__ __launch_bounds__(256) void k_scan(const int* __restrict__ cnt,
                                              int* __restrict__ rowptr,
                                              int* __restrict__ cursor) {
  int t = blockIdx.x;
  int lane = threadIdx.x & 63, wid = threadIdx.x >> 6;
  __shared__ int wsum[4];
  __shared__ int carry_s;
  if (threadIdx.x == 0) carry_s = 0;
  __syncthreads();
  for (int base = 0; base < N; base += 256) {
    int i = base + threadIdx.x;
    int v = (i < N) ? cnt[t * N + i] : 0;
    int s = v;
    #pragma unroll
    for (int off = 1; off < 64; off <<= 1) {
      int u = __shfl_up(s, off, 64);
      if (lane >= off) s += u;
    }
    if (lane == 63) wsum[wid] = s;
    int carry = carry_s;
    __syncthreads();
    int wadd = 0;
    #pragma unroll
    for (int w = 0; w < 4; ++w) if (w < wid) wadd += wsum[w];
    int excl = carry + wadd + s - v;
    if (i < N) { rowptr[t * N + i] = excl; cursor[t * N + i] = excl; }
    __syncthreads();
    if (threadIdx.x == 0) carry_s = carry + wsum[0] + wsum[1] + wsum[2] + wsum[3];
    __syncthreads();
  }
}

// counting sort pass 2: place packed (src, ew*dinv[src]) records by dst
__global__ __launch_bounds__(256) void k_fill(const int* __restrict__ ei,
                                              const float* __restrict__ ew,
                                              const float* __restrict__ dinv,
                                              int* __restrict__ cursor,
                                              int2* __restrict__ pk) {
  int i = blockIdx.x * 256 + threadIdx.x;
  if (i >= T * E) return;
  int t = i / E, e = i - t * E;
  const int* eit = ei + (size_t)t * 2 * E;
  int src = eit[e];
  int dst = eit[E + e];
  float w = ew[(size_t)t * E + e] * dinv[t * N + src];
  int pos = atomicAdd(&cursor[t * N + dst], 1);
  int2 rec;
  rec.x = src;
  rec.y = __float_as_int(w);
  pk[(size_t)t * E + pos] = rec;
}

// ---------------------------------------------------------------- weight prep: fp32 -> bf16 into one buffer
// Wb layout: [0,8192) gcn1_w; [8192,12288) gcn2_w; [12288,24576) in_w; [24576,28672) out_w; [28672,32768) fc_w
__global__ __launch_bounds__(256) void k_prep(const float* __restrict__ g1w,
                                              const float* __restrict__ g2w,
                                              const float* __restrict__ inw,
                                              const float* __restrict__ outw,
                                              const float* __restrict__ fcw,
                                              unsigned short* __restrict__ Wb) {
  int i = blockIdx.x * 256 + threadIdx.x;
  if (i >= 32768) return;
  const float* src;
  int off;
  if (i < 8192)       { src = g1w;  off = 0; }
  else if (i < 12288) { src = g2w;  off = 8192; }
  else if (i < 24576) { src = inw;  off = 12288; }
  else if (i < 28672) { src = outw; off = 24576; }
  else                { src = fcw;  off = 28672; }
  Wb[i] = f2bf(src[i - off]);
}

// ---------------------------------------------------------------- MFMA GEMM: out[m][j] = sum_k W[j][k] * B[m][k]
// A-operand = weight rows (M-dim = output feature j), B-operand = data rows (N-dim = m).
// C/D layout (16x16x32): col = lane&15 -> m; row = quad*4+reg -> j. So each lane owns
// 4 CONSECUTIVE output features of one data row -> single b64 bf16 store, no transpose.
// MODE 0: plain store out[m][NT*16]. MODE 1 (qkv, NT=12): jt<4 = q (store rows with t==9
// to q9[r][64]); jt>=4 = k,v -> out = kv[m][128]; bias added from biasp.
template <int K, int NT, bool BF16B, int MODE>
__global__ __launch_bounds__(256) void k_mm(const unsigned short* __restrict__ Wb,
                                            const void* __restrict__ Bv,
                                            const float* __restrict__ biasp,
                                            unsigned short* __restrict__ out,
                                            unsigned short* __restrict__ q9,
                                            int Mwaves) {
  int wv = threadIdx.x >> 6, lane = threadIdx.x & 63;
  int wave = blockIdx.x * 4 + wv;
  if (wave >= Mwaves) return;
  int m0 = wave * 16;
  int half = lane & 15, quad = lane >> 4;
  constexpr int KS = K / 32;
  int m = m0 + half;
  // B-frags: lane holds data row m, k = ks*32 + quad*8 .. +8
  bf16x8 bfrag[KS];
  if (BF16B) {
    const unsigned short* Bp = (const unsigned short*)Bv + (size_t)m * K + quad * 8;
    #pragma unroll
    for (int ks = 0; ks < KS; ++ks) bfrag[ks] = *(const bf16x8*)(Bp + ks * 32);
  } else {
    const float* Bp = (const float*)Bv + (size_t)m * K + quad * 8;
    #pragma unroll
    for (int ks = 0; ks < KS; ++ks) {
      float4 f0 = *(const float4*)(Bp + ks * 32);
      float4 f1 = *(const float4*)(Bp + ks * 32 + 4);
      bf16x8 b;
      b[0] = (short)f2bf(f0.x); b[1] = (short)f2bf(f0.y);
      b[2] = (short)f2bf(f0.z); b[3] = (short)f2bf(f0.w);
      b[4] = (short)f2bf(f1.x); b[5] = (short)f2bf(f1.y);
      b[6] = (short)f2bf(f1.z); b[7] = (short)f2bf(f1.w);
      bfrag[ks] = b;
    }
  }
  #pragma unroll
  for (int jt = 0; jt < NT; ++jt) {
    f32x4 acc = {0.f, 0.f, 0.f, 0.f};
    const unsigned short* Wp = Wb + (size_t)(jt * 16 + half) * K + quad * 8;
    #pragma unroll
    for (int ks = 0; ks < KS; ++ks) {
      bf16x8 afrag = *(const bf16x8*)(Wp + ks * 32);
      acc = __builtin_amdgcn_mfma_f32_16x16x32_bf16(afrag, bfrag[ks], acc, 0, 0, 0);
    }
    int j = jt * 16 + quad * 4;
    if (MODE == 1) {
      float4 b4 = *(const float4*)(biasp + j);
      acc[0] += b4.x; acc[1] += b4.y; acc[2] += b4.z; acc[3] += b4.w;
    }
    ushort4 o;
    o.x = f2bf(acc[0]); o.y = f2bf(acc[1]); o.z = f2bf(acc[2]); o.w = f2bf(acc[3]);
    if (MODE == 0) {
      *(ushort4*)(out + (size_t)m * (NT * 16) + j) = o;
    } else {
      if (jt < 4) {
        if (m % 10 == 9) *(ushort4*)(q9 + (size_t)(m / 10) * 64 + j) = o;
      } else {
        *(ushort4*)(out + (size_t)m * 128 + (j - 64)) = o;
      }
    }
  }
}

// ---------------------------------------------------------------- GCN aggregation (unchanged from round 2)
template <bool SCATTER>
__global__ __launch_bounds__(256) void k_gather(
    const unsigned short* __restrict__ hw, const int2* __restrict__ pk,
    const float* __restrict__ dinv, const int* __restrict__ rowptr,
    const int* __restrict__ cnt, const float* __restrict__ bias,
    const int* __restrict__ gidx, unsigned short* __restrict__ outp) {
  int wv = threadIdx.x >> 6, lane = threadIdx.x & 63;
  long long wave = (long long)blockIdx.x * 4 + wv;
  if (wave >= (long long)T * N) return;
  int t = (int)(wave / N);
  int n = (int)(wave - (long long)t * N);
  const unsigned short* hwt = hw + (size_t)t * N * D;
  const int2* pkt = pk + (size_t)t * E;
  float dn = dinv[t * N + n];
  int start = rowptr[t * N + n];
  int m = cnt[t * N + n];
  int grp = lane >> 4, sub = lane & 15;
  float4 acc0 = make_float4(0.f, 0.f, 0.f, 0.f);
  float4 acc1 = make_float4(0.f, 0.f, 0.f, 0.f);
  for (int b = 0; b < m; b += 64) {
    int mm = min(64, m - b);
    int2 rec = make_int2(0, 0);
    if (lane < mm) rec = pkt[start + b + lane];
    int s_l = rec.x;
    float w_l = __int_as_float(rec.y);
    int iters = (mm + 3) >> 2;
    int i = 0;
    for (; i + 2 <= iters; i += 2) {
      int i0 = 4 * i + grp;
      int i1 = i0 + 4;
      int sa = __shfl(s_l, i0, 64);
      float wa = __shfl(w_l, i0, 64);
      int sb = __shfl(s_l, i1, 64);
      float wb = __shfl(w_l, i1, 64);
      ushort4 ha = *(const ushort4*)(hwt + (size_t)sa * D + (sub << 2));
      ushort4 hb = *(const ushort4*)(hwt + (size_t)sb * D + (sub << 2));
      acc0.x = fmaf(wa, bf2f(ha.x), acc0.x);
      acc0.y = fmaf(wa, bf2f(ha.y), acc0.y);
      acc0.z = fmaf(wa, bf2f(ha.z), acc0.z);
      acc0.w = fmaf(wa, bf2f(ha.w), acc0.w);
      acc1.x = fmaf(wb, bf2f(hb.x), acc1.x);
      acc1.y = fmaf(wb, bf2f(hb.y), acc1.y);
      acc1.z = fmaf(wb, bf2f(hb.z), acc1.z);
      acc1.w = fmaf(wb, bf2f(hb.w), acc1.w);
    }
    if (i < iters) {
      int i0 = 4 * i + grp;
      int sa = __shfl(s_l, i0, 64);
      float wa = __shfl(w_l, i0, 64);
      ushort4 ha = *(const ushort4*)(hwt + (size_t)sa * D + (sub << 2));
      acc0.x = fmaf(wa, bf2f(ha.x), acc0.x);
      acc0.y = fmaf(wa, bf2f(ha.y), acc0.y);
      acc0.z = fmaf(wa, bf2f(ha.z), acc0.z);
      acc0.w = fmaf(wa, bf2f(ha.w), acc0.w);
    }
  }
  acc0.x += acc1.x; acc0.y += acc1.y; acc0.z += acc1.z; acc0.w += acc1.w;
  acc0.x += __shfl_xor(acc0.x, 16, 64); acc0.x += __shfl_xor(acc0.x, 32, 64);
  acc0.y += __shfl_xor(acc0.y, 16, 64); acc0.y += __shfl_xor(acc0.y, 32, 64);
  acc0.z += __shfl_xor(acc0.z, 16, 64); acc0.z += __shfl_xor(acc0.z, 32, 64);
  acc0.w += __shfl_xor(acc0.w, 16, 64); acc0.w += __shfl_xor(acc0.w, 32, 64);
  if (grp == 0) {
    ushort4 sv = *(const ushort4*)(hwt + (size_t)n * D + (sub << 2));
    float4 b4 = *(const float4*)(bias + (sub << 2));
    float dnn = dn * dn;
    float vx = fmaxf(fmaf(acc0.x, dn, fmaf(dnn, bf2f(sv.x), b4.x)), 0.f);
    float vy = fmaxf(fmaf(acc0.y, dn, fmaf(dnn, bf2f(sv.y), b4.y)), 0.f);
    float vz = fmaxf(fmaf(acc0.z, dn, fmaf(dnn, bf2f(sv.z), b4.z)), 0.f);
    float vw = fmaxf(fmaf(acc0.w, dn, fmaf(dnn, bf2f(sv.w), b4.w)), 0.f);
    ushort4 o;
    o.x = f2bf(vx); o.y = f2bf(vy); o.z = f2bf(vz); o.w = f2bf(vw);
    size_t ro;
    if (SCATTER) {
      int rr = gidx[(size_t)t * R + n];
      ro = ((size_t)rr * T + t) * D;
    } else {
      ro = ((size_t)t * N + n) * D;
    }
    *(ushort4*)(outp + ro + (sub << 2)) = o;
  }
}

// ---------------------------------------------------------------- attention core: one wave per r.
// mask is all-present (global_idx is a permutation), q only at t=T-1. Reads are coalesced
// (2560 B contiguous kv per r). No weights, no LDS.
__global__ __launch_bounds__(256) void k_attn2(const unsigned short* __restrict__ kv,
                                               const unsigned short* __restrict__ q9,
                                               unsigned short* __restrict__ ao) {
  int wv = threadIdx.x >> 6, lane = threadIdx.x & 63;
  int r = blockIdx.x * 4 + wv;
  if (r >= R) return;
  float qv = bf2f(q9[(size_t)r * 64 + lane]);
  const unsigned short* kvr = kv + (size_t)r * T * 128;
  float sc[T], vv[T];
  #pragma unroll
  for (int s = 0; s < T; ++s) {
    float kk = bf2f(kvr[s * 128 + lane]);
    vv[s] = bf2f(kvr[s * 128 + 64 + lane]);
    float p = qv * kk;
    p += __shfl_xor(p, 8, 16);
    p += __shfl_xor(p, 4, 16);
    p += __shfl_xor(p, 2, 16);
    p += __shfl_xor(p, 1, 16);
    sc[s] = p * 0.25f;  // 1/sqrt(16)
  }
  float mx = sc[0];
  #pragma unroll
  for (int s = 1; s < T; ++s) mx = fmaxf(mx, sc[s]);
  float ssum = 0.f;
  #pragma unroll
  for (int s = 0; s < T; ++s) { sc[s] = expf(sc[s] - mx); ssum += sc[s]; }
  float rinv = 1.0f / ssum;
  float aov = 0.f;
  #pragma unroll
  for (int s = 0; s < T; ++s) aov = fmaf(sc[s] * rinv, vv[s], aov);
  ao[(size_t)r * 64 + lane] = f2bf(aov);
}

// ---------------------------------------------------------------- LN1: fin = LN(w1⊙te9 + w2⊙(proj+outB))
__global__ __launch_bounds__(256) void k_ln1(const unsigned short* __restrict__ te,
                                             const unsigned short* __restrict__ proj,
                                             const float* __restrict__ outB,
                                             const float* __restrict__ w1,
                                             const float* __restrict__ w2,
                                             const float* __restrict__ g1,
                                             const float* __restrict__ b1,
                                             float* __restrict__ finf,
                                             unsigned short* __restrict__ finb) {
  int wv = threadIdx.x >> 6, lane = threadIdx.x & 63;
  int r = blockIdx.x * 4 + wv;
  if (r >= R) return;
  float t9 = bf2f(te[((size_t)r * T + (T - 1)) * 64 + lane]);
  float pr = bf2f(proj[(size_t)r * 64 + lane]) + outB[lane];
  float pre = w1[(T - 1) * 64 + lane] * t9 + w2[(T - 1) * 64 + lane] * pr;
  float s1 = pre;
  #pragma unroll
  for (int off = 32; off >= 1; off >>= 1) s1 += __shfl_xor(s1, off, 64);
  float mu = s1 * (1.0f / 64.0f);
  float dv = pre - mu;
  float s2 = dv * dv;
  #pragma unroll
  for (int off = 32; off >= 1; off >>= 1) s2 += __shfl_xor(s2, off, 64);
  float rstd = 1.0f / sqrtf(s2 * (1.0f / 64.0f) + 1e-5f);
  float fin = dv * rstd * g1[lane] + b1[lane];
  finf[(size_t)r * 64 + lane] = fin;
  finb[(size_t)r * 64 + lane] = f2bf(fin);
}

// ---------------------------------------------------------------- LN2: out = LN(w3⊙fin + w4⊙(o2+fcB))
__global__ __launch_bounds__(256) void k_ln2(const float* __restrict__ finf,
                                             const unsigned short* __restrict__ o2,
                                             const float* __restrict__ fcB,
                                             const float* __restrict__ w3,
                                             const float* __restrict__ w4,
                                             const float* __restrict__ g2,
                                             const float* __restrict__ b2,
                                             float* __restrict__ out) {
  int wv = threadIdx.x >> 6, lane = threadIdx.x & 63;
  int r = blockIdx.x * 4 + wv;
  if (r >= R) return;
  float fin = finf[(size_t)r * 64 + lane];
  float oo = bf2f(o2[(size_t)r * 64 + lane]) + fcB[lane];
  float pre = w3[lane] * fin + w4[lane] * oo;
  float s1 = pre;
  #pragma unroll
  for (int off = 32; off >= 1; off >>= 1) s1 += __shfl_xor(s1, off, 64);
  float mu = s1 * (1.0f / 64.0f);
  float dv = pre - mu;
  float s2 = dv * dv;
  #pragma unroll
  for (int off = 32; off >= 1; off >>= 1) s2 += __shfl_xor(s2, off, 64);
  float rstd = 1.0f / sqrtf(s2 * (1.0f / 64.0f) + 1e-5f);
  out[(size_t)r * 64 + lane] = dv * rstd * g2[lane] + b2[lane];
}

}  // namespace

extern "C" void kernel_launch(void* const* d_in, const int* in_sizes, int n_in,
                              void* d_out, int out_size, void* d_ws, size_t ws_size,
                              hipStream_t stream) {
  const float* x      = (const float*)d_in[0];
  const int*   ei     = (const int*)d_in[1];
  const float* ew     = (const float*)d_in[2];
  const int*   gidx   = (const int*)d_in[3];
  const float* gcn1_w = (const float*)d_in[4];
  const float* gcn1_b = (const float*)d_in[5];
  const float* gcn2_w = (const float*)d_in[6];
  const float* gcn2_b = (const float*)d_in[7];
  const float* in_w   = (const float*)d_in[8];
  const float* in_b   = (const float*)d_in[9];
  const float* out_w  = (const float*)d_in[10];
  const float* out_b  = (const float*)d_in[11];
  const float* w1     = (const float*)d_in[12];
  const float* w2     = (const float*)d_in[13];
  const float* w3     = (const float*)d_in[14];
  const float* w4     = (const float*)d_in[15];
  const float* ln1_g  = (const float*)d_in[16];
  const float* ln1_b  = (const float*)d_in[17];
  const float* ln2_g  = (const float*)d_in[18];
  const float* ln2_b  = (const float*)d_in[19];
  const float* fc_w   = (const float*)d_in[20];
  const float* fc_b   = (const float*)d_in[21];
  float* outp = (float*)d_out;

  char* ws = (char*)d_ws;
  size_t off = 0;
  auto alloc = [&](size_t bytes) {
    void* p = ws + off;
    off += (bytes + 255) & ~(size_t)255;
    return p;
  };
  // persistent-tail region
  unsigned short* h1te = (unsigned short*)alloc(sizeof(short) * (size_t)T * N * D);  // h1 / time_embeds
  unsigned short* q9b  = (unsigned short*)alloc(sizeof(short) * (size_t)R * D);
  unsigned short* aob  = (unsigned short*)alloc(sizeof(short) * (size_t)R * D);
  unsigned short* proj = (unsigned short*)alloc(sizeof(short) * (size_t)R * D);
  float*          finf = (float*)alloc(sizeof(float) * (size_t)R * D);
  unsigned short* finb = (unsigned short*)alloc(sizeof(short) * (size_t)R * D);
  unsigned short* o2b  = (unsigned short*)alloc(sizeof(short) * (size_t)R * D);
  unsigned short* Wb   = (unsigned short*)alloc(sizeof(short) * 32768);
  // union region: {graph-prep + hw} (dead after gather2) aliased with kv (live after)
  size_t u_base = off;
  float* deg    = (float*)alloc(sizeof(float) * T * N);
  int*   cnt    = (int*)alloc(sizeof(int) * T * N);
  int*   rowptr = (int*)alloc(sizeof(int) * T * N);
  int*   cursor = (int*)alloc(sizeof(int) * T * N);
  int2*  pk     = (int2*)alloc(sizeof(int2) * (size_t)T * E);
  unsigned short* hw = (unsigned short*)alloc(sizeof(short) * (size_t)T * N * D);
  unsigned short* kv = (unsigned short*)(ws + u_base);  // [T*N][128] bf16, aliases the above

  const unsigned short* W1b = Wb;           // gcn1_w  [64][128]
  const unsigned short* W2b = Wb + 8192;    // gcn2_w  [64][64]
  const unsigned short* WIb = Wb + 12288;   // in_w    [192][64]
  const unsigned short* WOb = Wb + 24576;   // out_w   [64][64]
  const unsigned short* WFb = Wb + 28672;   // fc_w    [64][64]

  const int M = T * N;
  const int MW = M / 16;   // 31250
  const int RW = R / 16;   // 3125

  k_init<<<(T * N + 255) / 256, 256, 0, stream>>>(deg, cnt);
  k_edge_count<<<(T * E + 255) / 256, 256, 0, stream>>>(ei, ew, deg, cnt);
  k_dinv<<<(T * N + 255) / 256, 256, 0, stream>>>(deg);
  k_scan<<<T, 256, 0, stream>>>(cnt, rowptr, cursor);
  k_fill<<<(T * E + 255) / 256, 256, 0, stream>>>(ei, ew, deg, cursor, pk);
  k_prep<<<128, 256, 0, stream>>>(gcn1_w, gcn2_w, in_w, out_w, fc_w, Wb);

  // GCN stage
  k_mm<DIN, 4, false, 0><<<(MW + 3) / 4, 256, 0, stream>>>(W1b, x, nullptr, hw, nullptr, MW);
  k_gather<false><<<(M + 3) / 4, 256, 0, stream>>>(hw, pk, deg, rowptr, cnt, gcn1_b,
                                                   nullptr, h1te);
  k_mm<D, 4, true, 0><<<(MW + 3) / 4, 256, 0, stream>>>(W2b, h1te, nullptr, hw, nullptr, MW);
  k_gather<true><<<(M + 3) / 4, 256, 0, stream>>>(hw, pk, deg, rowptr, cnt, gcn2_b,
                                                  gidx, h1te);  // -> time_embeds (bf16)

  // attention tail (hw/pk/etc. now dead; kv aliases them)
  k_mm<D, 12, true, 1><<<(MW + 3) / 4, 256, 0, stream>>>(WIb, h1te, in_b, kv, q9b, MW);
  k_attn2<<<(R + 3) / 4, 256, 0, stream>>>(kv, q9b, aob);
  k_mm<D, 4, true, 0><<<(RW + 3) / 4, 256, 0, stream>>>(WOb, aob, nullptr, proj, nullptr, RW);
  k_ln1<<<(R + 3) / 4, 256, 0, stream>>>(h1te, proj, out_b, w1, w2, ln1_g, ln1_b, finf, finb);
  k_mm<D, 4, true, 0><<<(RW + 3) / 4, 256, 0, stream>>>(WFb, finb, nullptr, o2b, nullptr, RW);
  k_ln2<<<(R + 3) / 4, 256, 0, stream>>>(finf, o2b, fc_b, w3, w4, ln2_g, ln2_b, outp);
}

// Round 4
// 1602.962 us; speedup vs baseline: 1.5094x; 1.0513x over previous
//
#include <hip/hip_runtime.h>
#include <cstdint>
#include <cstddef>

namespace {

constexpr int T = 10;
constexpr int N = 50000;
constexpr int R = 50000;
constexpr int DIN = 128;
constexpr int D = 64;
constexpr int E = 400000;

// LDS-binned edge-prep geometry
constexpr int BINS = 8192;              // bins per range (LDS-resident)
constexpr int NR = 7;                   // ranges: 7*8192 = 57344 >= N
constexpr int SEG = 8;                  // edge segments per t
constexpr int ESEG = E / SEG;           // 50000 edges per segment

typedef __attribute__((ext_vector_type(8))) short bf16x8;
typedef __attribute__((ext_vector_type(4))) float f32x4;

__device__ __forceinline__ float bf2f(unsigned short u) {
  return __uint_as_float(((unsigned)u) << 16);
}
__device__ __forceinline__ unsigned short f2bf(float f) {
  unsigned u = __float_as_uint(f);
  return (unsigned short)((u + 0x7FFFu + ((u >> 16) & 1u)) >> 16);
}

// ---------------------------------------------------------------- pass A: LDS histogram
// block = (t, range, seg). No global atomics: per-block partials written coalesced.
__global__ __launch_bounds__(256) void k_hist(const int* __restrict__ ei,
                                              const float* __restrict__ ew,
                                              unsigned* __restrict__ pcnt,
                                              float* __restrict__ pdeg) {
  __shared__ unsigned cnt_l[BINS];
  __shared__ float deg_l[BINS];
  int b = blockIdx.x;
  int s = b % SEG;
  int tr = b / SEG;
  int r = tr % NR;
  int t = tr / NR;
  for (int i = threadIdx.x; i < BINS; i += 256) { cnt_l[i] = 0u; deg_l[i] = 0.f; }
  __syncthreads();
  int bin0 = r * BINS;
  const int* dstp = ei + (size_t)t * 2 * E + E;
  const float* ewp = ew + (size_t)t * E;
  int e0 = s * ESEG, e1 = e0 + ESEG;
  for (int e = e0 + threadIdx.x; e < e1; e += 256) {
    int d = dstp[e];
    float w = ewp[e];
    unsigned rel = (unsigned)(d - bin0);
    if (rel < (unsigned)BINS) {
      atomicAdd(&cnt_l[rel], 1u);   // ds_add
      atomicAdd(&deg_l[rel], w);    // ds_add_f32
    }
  }
  __syncthreads();
  size_t base = (size_t)b * BINS;
  for (int i = threadIdx.x; i < BINS; i += 256) {
    pcnt[base + i] = cnt_l[i];
    pdeg[base + i] = deg_l[i];
  }
}

// ---------------------------------------------------------------- pass B: reduce partials -> cnt, dinv
__global__ __launch_bounds__(256) void k_hreduce(const unsigned* __restrict__ pcnt,
                                                 const float* __restrict__ pdeg,
                                                 int* __restrict__ cnt,
                                                 float* __restrict__ dinv) {
  int i = blockIdx.x * 256 + threadIdx.x;
  if (i >= T * N) return;
  int t = i / N, n = i - t * N;
  int r = n / BINS, rel = n - r * BINS;
  unsigned c = 0;
  float dg = 1.0f;  // self-loop weight
  #pragma unroll
  for (int s = 0; s < SEG; ++s) {
    size_t base = ((size_t)((t * NR + r) * SEG + s)) * BINS + rel;
    c += pcnt[base];
    dg += pdeg[base];
  }
  cnt[i] = (int)c;
  dinv[i] = rsqrtf(dg);  // dg >= 1 always
}

// per-t exclusive scan of cnt -> rowptr (one block per t)
__global__ __launch_bounds__(256) void k_scan(const int* __restrict__ cnt,
                                              int* __restrict__ rowptr) {
  int t = blockIdx.x;
  int lane = threadIdx.x & 63, wid = threadIdx.x >> 6;
  __shared__ int wsum[4];
  __shared__ int carry_s;
  if (threadIdx.x == 0) carry_s = 0;
  __syncthreads();
  for (int base = 0; base < N; base += 256) {
    int i = base + threadIdx.x;
    int v = (i < N) ? cnt[t * N + i] : 0;
    int s = v;
    #pragma unroll
    for (int off = 1; off < 64; off <<= 1) {
      int u = __shfl_up(s, off, 64);
      if (lane >= off) s += u;
    }
    if (lane == 63) wsum[wid] = s;
    int carry = carry_s;
    __syncthreads();
    int wadd = 0;
    #pragma unroll
    for (int w = 0; w < 4; ++w) if (w < wid) wadd += wsum[w];
    if (i < N) rowptr[t * N + i] = carry + wadd + s - v;
    __syncthreads();
    if (threadIdx.x == 0) carry_s = carry + wsum[0] + wsum[1] + wsum[2] + wsum[3];
    __syncthreads();
  }
}

// ---------------------------------------------------------------- pass C: partial counts -> absolute seg cursors (in place)
__global__ __launch_bounds__(256) void k_segoff(unsigned* __restrict__ pcnt,
                                                const int* __restrict__ rowptr) {
  int i = blockIdx.x * 256 + threadIdx.x;
  if (i >= T * N) return;
  int t = i / N, n = i - t * N;
  int r = n / BINS, rel = n - r * BINS;
  unsigned run = (unsigned)rowptr[i];
  #pragma unroll
  for (int s = 0; s < SEG; ++s) {
    size_t base = ((size_t)((t * NR + r) * SEG + s)) * BINS + rel;
    unsigned c = pcnt[base];
    pcnt[base] = run;
    run += c;
  }
}

// ---------------------------------------------------------------- pass D: place packed (src, ew*dinv[src]) via LDS cursors
__global__ __launch_bounds__(256) void k_fill2(const int* __restrict__ ei,
                                               const float* __restrict__ ew,
                                               const float* __restrict__ dinv,
                                               const unsigned* __restrict__ pcnt,
                                               int2* __restrict__ pk) {
  __shared__ int cur[BINS];
  int b = blockIdx.x;
  int s = b % SEG;
  int tr = b / SEG;
  int r = tr % NR;
  int t = tr / NR;
  size_t pbase = (size_t)b * BINS;
  for (int i = threadIdx.x; i < BINS; i += 256) cur[i] = (int)pcnt[pbase + i];
  __syncthreads();
  int bin0 = r * BINS;
  const int* srcp = ei + (size_t)t * 2 * E;
  const int* dstp = srcp + E;
  const float* ewp = ew + (size_t)t * E;
  const float* dinvt = dinv + (size_t)t * N;
  int2* pkt = pk + (size_t)t * E;
  int e0 = s * ESEG, e1 = e0 + ESEG;
  for (int e = e0 + threadIdx.x; e < e1; e += 256) {
    int d = dstp[e];
    unsigned rel = (unsigned)(d - bin0);
    if (rel < (unsigned)BINS) {
      int src = srcp[e];
      float w = ewp[e] * dinvt[src];
      int pos = atomicAdd(&cur[rel], 1);
      int2 rec;
      rec.x = src;
      rec.y = __float_as_int(w);
      pkt[pos] = rec;
    }
  }
}

// ---------------------------------------------------------------- weight prep: fp32 -> bf16 into one buffer
__global__ __launch_bounds__(256) void k_prep(const float* __restrict__ g1w,
                                              const float* __restrict__ g2w,
                                              const float* __restrict__ inw,
                                              const float* __restrict__ outw,
                                              const float* __restrict__ fcw,
                                              unsigned short* __restrict__ Wb) {
  int i = blockIdx.x * 256 + threadIdx.x;
  if (i >= 32768) return;
  const float* src;
  int off;
  if (i < 8192)       { src = g1w;  off = 0; }
  else if (i < 12288) { src = g2w;  off = 8192; }
  else if (i < 24576) { src = inw;  off = 12288; }
  else if (i < 28672) { src = outw; off = 24576; }
  else                { src = fcw;  off = 28672; }
  Wb[i] = f2bf(src[i - off]);
}

// ---------------------------------------------------------------- MFMA GEMM: out[m][j] = sum_k W[j][k] * B[m][k]
// A = weight rows (M-dim = output feature j), B = data rows (N-dim = m). C/D layout
// (16x16x32): col = lane&15 -> m; row = quad*4+reg -> j: lane owns 4 consecutive
// features of one row -> b64 bf16 store, no transpose.
template <int K, int NT, bool BF16B, int MODE>
__global__ __launch_bounds__(256) void k_mm(const unsigned short* __restrict__ Wb,
                                            const void* __restrict__ Bv,
                                            const float* __restrict__ biasp,
                                            unsigned short* __restrict__ out,
                                            unsigned short* __restrict__ q9,
                                            int Mwaves) {
  int wv = threadIdx.x >> 6, lane = threadIdx.x & 63;
  int wave = blockIdx.x * 4 + wv;
  if (wave >= Mwaves) return;
  int m0 = wave * 16;
  int half = lane & 15, quad = lane >> 4;
  constexpr int KS = K / 32;
  int m = m0 + half;
  bf16x8 bfrag[KS];
  if (BF16B) {
    const unsigned short* Bp = (const unsigned short*)Bv + (size_t)m * K + quad * 8;
    #pragma unroll
    for (int ks = 0; ks < KS; ++ks) bfrag[ks] = *(const bf16x8*)(Bp + ks * 32);
  } else {
    const float* Bp = (const float*)Bv + (size_t)m * K + quad * 8;
    #pragma unroll
    for (int ks = 0; ks < KS; ++ks) {
      float4 f0 = *(const float4*)(Bp + ks * 32);
      float4 f1 = *(const float4*)(Bp + ks * 32 + 4);
      bf16x8 b;
      b[0] = (short)f2bf(f0.x); b[1] = (short)f2bf(f0.y);
      b[2] = (short)f2bf(f0.z); b[3] = (short)f2bf(f0.w);
      b[4] = (short)f2bf(f1.x); b[5] = (short)f2bf(f1.y);
      b[6] = (short)f2bf(f1.z); b[7] = (short)f2bf(f1.w);
      bfrag[ks] = b;
    }
  }
  #pragma unroll
  for (int jt = 0; jt < NT; ++jt) {
    f32x4 acc = {0.f, 0.f, 0.f, 0.f};
    const unsigned short* Wp = Wb + (size_t)(jt * 16 + half) * K + quad * 8;
    #pragma unroll
    for (int ks = 0; ks < KS; ++ks) {
      bf16x8 afrag = *(const bf16x8*)(Wp + ks * 32);
      acc = __builtin_amdgcn_mfma_f32_16x16x32_bf16(afrag, bfrag[ks], acc, 0, 0, 0);
    }
    int j = jt * 16 + quad * 4;
    if (MODE == 1) {
      float4 b4 = *(const float4*)(biasp + j);
      acc[0] += b4.x; acc[1] += b4.y; acc[2] += b4.z; acc[3] += b4.w;
    }
    ushort4 o;
    o.x = f2bf(acc[0]); o.y = f2bf(acc[1]); o.z = f2bf(acc[2]); o.w = f2bf(acc[3]);
    if (MODE == 0) {
      *(ushort4*)(out + (size_t)m * (NT * 16) + j) = o;
    } else {
      if (jt < 4) {
        if (m % 10 == 9) *(ushort4*)(q9 + (size_t)(m / 10) * 64 + j) = o;
      } else {
        *(ushort4*)(out + (size_t)m * 128 + (j - 64)) = o;
      }
    }
  }
}

// ---------------------------------------------------------------- GCN aggregation (gather over CSR)
template <bool SCATTER>
__global__ __launch_bounds__(256) void k_gather(
    const unsigned short* __restrict__ hw, const int2* __restrict__ pk,
    const float* __restrict__ dinv, const int* __restrict__ rowptr,
    const int* __restrict__ cnt, const float* __restrict__ bias,
    const int* __restrict__ gidx, unsigned short* __restrict__ outp) {
  int wv = threadIdx.x >> 6, lane = threadIdx.x & 63;
  long long wave = (long long)blockIdx.x * 4 + wv;
  if (wave >= (long long)T * N) return;
  int t = (int)(wave / N);
  int n = (int)(wave - (long long)t * N);
  const unsigned short* hwt = hw + (size_t)t * N * D;
  const int2* pkt = pk + (size_t)t * E;
  float dn = dinv[t * N + n];
  int start = rowptr[t * N + n];
  int m = cnt[t * N + n];
  int grp = lane >> 4, sub = lane & 15;
  float4 acc0 = make_float4(0.f, 0.f, 0.f, 0.f);
  float4 acc1 = make_float4(0.f, 0.f, 0.f, 0.f);
  for (int b = 0; b < m; b += 64) {
    int mm = min(64, m - b);
    int2 rec = make_int2(0, 0);
    if (lane < mm) rec = pkt[start + b + lane];
    int s_l = rec.x;
    float w_l = __int_as_float(rec.y);
    int iters = (mm + 3) >> 2;
    int i = 0;
    for (; i + 2 <= iters; i += 2) {
      int i0 = 4 * i + grp;
      int i1 = i0 + 4;
      int sa = __shfl(s_l, i0, 64);
      float wa = __shfl(w_l, i0, 64);
      int sb = __shfl(s_l, i1, 64);
      float wb = __shfl(w_l, i1, 64);
      ushort4 ha = *(const ushort4*)(hwt + (size_t)sa * D + (sub << 2));
      ushort4 hb = *(const ushort4*)(hwt + (size_t)sb * D + (sub << 2));
      acc0.x = fmaf(wa, bf2f(ha.x), acc0.x);
      acc0.y = fmaf(wa, bf2f(ha.y), acc0.y);
      acc0.z = fmaf(wa, bf2f(ha.z), acc0.z);
      acc0.w = fmaf(wa, bf2f(ha.w), acc0.w);
      acc1.x = fmaf(wb, bf2f(hb.x), acc1.x);
      acc1.y = fmaf(wb, bf2f(hb.y), acc1.y);
      acc1.z = fmaf(wb, bf2f(hb.z), acc1.z);
      acc1.w = fmaf(wb, bf2f(hb.w), acc1.w);
    }
    if (i < iters) {
      int i0 = 4 * i + grp;
      int sa = __shfl(s_l, i0, 64);
      float wa = __shfl(w_l, i0, 64);
      ushort4 ha = *(const ushort4*)(hwt + (size_t)sa * D + (sub << 2));
      acc0.x = fmaf(wa, bf2f(ha.x), acc0.x);
      acc0.y = fmaf(wa, bf2f(ha.y), acc0.y);
      acc0.z = fmaf(wa, bf2f(ha.z), acc0.z);
      acc0.w = fmaf(wa, bf2f(ha.w), acc0.w);
    }
  }
  acc0.x += acc1.x; acc0.y += acc1.y; acc0.z += acc1.z; acc0.w += acc1.w;
  acc0.x += __shfl_xor(acc0.x, 16, 64); acc0.x += __shfl_xor(acc0.x, 32, 64);
  acc0.y += __shfl_xor(acc0.y, 16, 64); acc0.y += __shfl_xor(acc0.y, 32, 64);
  acc0.z += __shfl_xor(acc0.z, 16, 64); acc0.z += __shfl_xor(acc0.z, 32, 64);
  acc0.w += __shfl_xor(acc0.w, 16, 64); acc0.w += __shfl_xor(acc0.w, 32, 64);
  if (grp == 0) {
    ushort4 sv = *(const ushort4*)(hwt + (size_t)n * D + (sub << 2));
    float4 b4 = *(const float4*)(bias + (sub << 2));
    float dnn = dn * dn;
    float vx = fmaxf(fmaf(acc0.x, dn, fmaf(dnn, bf2f(sv.x), b4.x)), 0.f);
    float vy = fmaxf(fmaf(acc0.y, dn, fmaf(dnn, bf2f(sv.y), b4.y)), 0.f);
    float vz = fmaxf(fmaf(acc0.z, dn, fmaf(dnn, bf2f(sv.z), b4.z)), 0.f);
    float vw = fmaxf(fmaf(acc0.w, dn, fmaf(dnn, bf2f(sv.w), b4.w)), 0.f);
    ushort4 o;
    o.x = f2bf(vx); o.y = f2bf(vy); o.z = f2bf(vz); o.w = f2bf(vw);
    size_t ro;
    if (SCATTER) {
      int rr = gidx[(size_t)t * R + n];
      ro = ((size_t)rr * T + t) * D;
    } else {
      ro = ((size_t)t * N + n) * D;
    }
    *(ushort4*)(outp + ro + (sub << 2)) = o;
  }
}

// ---------------------------------------------------------------- attention core: one wave per r
__global__ __launch_bounds__(256) void k_attn2(const unsigned short* __restrict__ kv,
                                               const unsigned short* __restrict__ q9,
                                               unsigned short* __restrict__ ao) {
  int wv = threadIdx.x >> 6, lane = threadIdx.x & 63;
  int r = blockIdx.x * 4 + wv;
  if (r >= R) return;
  float qv = bf2f(q9[(size_t)r * 64 + lane]);
  const unsigned short* kvr = kv + (size_t)r * T * 128;
  float sc[T], vv[T];
  #pragma unroll
  for (int s = 0; s < T; ++s) {
    float kk = bf2f(kvr[s * 128 + lane]);
    vv[s] = bf2f(kvr[s * 128 + 64 + lane]);
    float p = qv * kk;
    p += __shfl_xor(p, 8, 16);
    p += __shfl_xor(p, 4, 16);
    p += __shfl_xor(p, 2, 16);
    p += __shfl_xor(p, 1, 16);
    sc[s] = p * 0.25f;  // 1/sqrt(16)
  }
  float mx = sc[0];
  #pragma unroll
  for (int s = 1; s < T; ++s) mx = fmaxf(mx, sc[s]);
  float ssum = 0.f;
  #pragma unroll
  for (int s = 0; s < T; ++s) { sc[s] = expf(sc[s] - mx); ssum += sc[s]; }
  float rinv = 1.0f / ssum;
  float aov = 0.f;
  #pragma unroll
  for (int s = 0; s < T; ++s) aov = fmaf(sc[s] * rinv, vv[s], aov);
  ao[(size_t)r * 64 + lane] = f2bf(aov);
}

// ---------------------------------------------------------------- LN1
__global__ __launch_bounds__(256) void k_ln1(const unsigned short* __restrict__ te,
                                             const unsigned short* __restrict__ proj,
                                             const float* __restrict__ outB,
                                             const float* __restrict__ w1,
                                             const float* __restrict__ w2,
                                             const float* __restrict__ g1,
                                             const float* __restrict__ b1,
                                             float* __restrict__ finf,
                                             unsigned short* __restrict__ finb) {
  int wv = threadIdx.x >> 6, lane = threadIdx.x & 63;
  int r = blockIdx.x * 4 + wv;
  if (r >= R) return;
  float t9 = bf2f(te[((size_t)r * T + (T - 1)) * 64 + lane]);
  float pr = bf2f(proj[(size_t)r * 64 + lane]) + outB[lane];
  float pre = w1[(T - 1) * 64 + lane] * t9 + w2[(T - 1) * 64 + lane] * pr;
  float s1 = pre;
  #pragma unroll
  for (int off = 32; off >= 1; off >>= 1) s1 += __shfl_xor(s1, off, 64);
  float mu = s1 * (1.0f / 64.0f);
  float dv = pre - mu;
  float s2 = dv * dv;
  #pragma unroll
  for (int off = 32; off >= 1; off >>= 1) s2 += __shfl_xor(s2, off, 64);
  float rstd = 1.0f / sqrtf(s2 * (1.0f / 64.0f) + 1e-5f);
  float fin = dv * rstd * g1[lane] + b1[lane];
  finf[(size_t)r * 64 + lane] = fin;
  finb[(size_t)r * 64 + lane] = f2bf(fin);
}

// ---------------------------------------------------------------- LN2
__global__ __launch_bounds__(256) void k_ln2(const float* __restrict__ finf,
                                             const unsigned short* __restrict__ o2,
                                             const float* __restrict__ fcB,
                                             const float* __restrict__ w3,
                                             const float* __restrict__ w4,
                                             const float* __restrict__ g2,
                                             const float* __restrict__ b2,
                                             float* __restrict__ out) {
  int wv = threadIdx.x >> 6, lane = threadIdx.x & 63;
  int r = blockIdx.x * 4 + wv;
  if (r >= R) return;
  float fin = finf[(size_t)r * 64 + lane];
  float oo = bf2f(o2[(size_t)r * 64 + lane]) + fcB[lane];
  float pre = w3[lane] * fin + w4[lane] * oo;
  float s1 = pre;
  #pragma unroll
  for (int off = 32; off >= 1; off >>= 1) s1 += __shfl_xor(s1, off, 64);
  float mu = s1 * (1.0f / 64.0f);
  float dv = pre - mu;
  float s2 = dv * dv;
  #pragma unroll
  for (int off = 32; off >= 1; off >>= 1) s2 += __shfl_xor(s2, off, 64);
  float rstd = 1.0f / sqrtf(s2 * (1.0f / 64.0f) + 1e-5f);
  out[(size_t)r * 64 + lane] = dv * rstd * g2[lane] + b2[lane];
}

}  // namespace

extern "C" void kernel_launch(void* const* d_in, const int* in_sizes, int n_in,
                              void* d_out, int out_size, void* d_ws, size_t ws_size,
                              hipStream_t stream) {
  const float* x      = (const float*)d_in[0];
  const int*   ei     = (const int*)d_in[1];
  const float* ew     = (const float*)d_in[2];
  const int*   gidx   = (const int*)d_in[3];
  const float* gcn1_w = (const float*)d_in[4];
  const float* gcn1_b = (const float*)d_in[5];
  const float* gcn2_w = (const float*)d_in[6];
  const float* gcn2_b = (const float*)d_in[7];
  const float* in_w   = (const float*)d_in[8];
  const float* in_b   = (const float*)d_in[9];
  const float* out_w  = (const float*)d_in[10];
  const float* out_b  = (const float*)d_in[11];
  const float* w1     = (const float*)d_in[12];
  const float* w2     = (const float*)d_in[13];
  const float* w3     = (const float*)d_in[14];
  const float* w4     = (const float*)d_in[15];
  const float* ln1_g  = (const float*)d_in[16];
  const float* ln1_b  = (const float*)d_in[17];
  const float* ln2_g  = (const float*)d_in[18];
  const float* ln2_b  = (const float*)d_in[19];
  const float* fc_w   = (const float*)d_in[20];
  const float* fc_b   = (const float*)d_in[21];
  float* outp = (float*)d_out;

  char* ws = (char*)d_ws;
  size_t off = 0;
  auto alloc = [&](size_t bytes) {
    void* p = ws + off;
    off += (bytes + 255) & ~(size_t)255;
    return p;
  };
  // persistent-tail region (~109 MB)
  unsigned short* h1te = (unsigned short*)alloc(sizeof(short) * (size_t)T * N * D);  // h1 / time_embeds
  unsigned short* q9b  = (unsigned short*)alloc(sizeof(short) * (size_t)R * D);
  unsigned short* aob  = (unsigned short*)alloc(sizeof(short) * (size_t)R * D);
  unsigned short* proj = (unsigned short*)alloc(sizeof(short) * (size_t)R * D);
  float*          finf = (float*)alloc(sizeof(float) * (size_t)R * D);
  unsigned short* finb = (unsigned short*)alloc(sizeof(short) * (size_t)R * D);
  unsigned short* o2b  = (unsigned short*)alloc(sizeof(short) * (size_t)R * D);
  unsigned short* Wb   = (unsigned short*)alloc(sizeof(short) * 32768);
  // union region: graph-prep (dead after gather2) aliased with kv (live after)
  size_t u_base = off;
  float* dinv   = (float*)alloc(sizeof(float) * T * N);
  int*   cnt    = (int*)alloc(sizeof(int) * T * N);
  int*   rowptr = (int*)alloc(sizeof(int) * T * N);
  int2*  pk     = (int2*)alloc(sizeof(int2) * (size_t)T * E);
  unsigned* pcnt = (unsigned*)alloc(sizeof(unsigned) * (size_t)T * NR * SEG * BINS);  // 18.35 MB
  size_t pdeg_off = off;
  float* pdeg = (float*)alloc(sizeof(float) * (size_t)T * NR * SEG * BINS);           // 18.35 MB
  // hw aliases pdeg (dead after k_hreduce) and extends beyond
  unsigned short* hw = (unsigned short*)(ws + pdeg_off);
  size_t hw_end = pdeg_off + sizeof(short) * (size_t)T * N * D;
  if (hw_end > off) off = hw_end;
  // kv aliases the whole union region (everything above dead after gather2)
  unsigned short* kv = (unsigned short*)(ws + u_base);  // [T*N][128] bf16 = 128 MB
  size_t kv_end = u_base + sizeof(short) * (size_t)T * N * 128;
  if (kv_end > off) off = kv_end;
  (void)pdeg;  // silence unused warnings if any

  const unsigned short* W1b = Wb;           // gcn1_w  [64][128]
  const unsigned short* W2b = Wb + 8192;    // gcn2_w  [64][64]
  const unsigned short* WIb = Wb + 12288;   // in_w    [192][64]
  const unsigned short* WOb = Wb + 24576;   // out_w   [64][64]
  const unsigned short* WFb = Wb + 28672;   // fc_w    [64][64]

  const int M = T * N;
  const int MW = M / 16;   // 31250
  const int RW = R / 16;   // 3125
  const int PREP_BLOCKS = T * NR * SEG;  // 560

  // graph prep — no global atomics
  k_hist<<<PREP_BLOCKS, 256, 0, stream>>>(ei, ew, pcnt, pdeg);
  k_hreduce<<<(T * N + 255) / 256, 256, 0, stream>>>(pcnt, pdeg, cnt, dinv);
  k_scan<<<T, 256, 0, stream>>>(cnt, rowptr);
  k_segoff<<<(T * N + 255) / 256, 256, 0, stream>>>(pcnt, rowptr);
  k_fill2<<<PREP_BLOCKS, 256, 0, stream>>>(ei, ew, dinv, pcnt, pk);
  k_prep<<<128, 256, 0, stream>>>(gcn1_w, gcn2_w, in_w, out_w, fc_w, Wb);

  // GCN stage
  k_mm<DIN, 4, false, 0><<<(MW + 3) / 4, 256, 0, stream>>>(W1b, x, nullptr, hw, nullptr, MW);
  k_gather<false><<<(M + 3) / 4, 256, 0, stream>>>(hw, pk, dinv, rowptr, cnt, gcn1_b,
                                                   nullptr, h1te);
  k_mm<D, 4, true, 0><<<(MW + 3) / 4, 256, 0, stream>>>(W2b, h1te, nullptr, hw, nullptr, MW);
  k_gather<true><<<(M + 3) / 4, 256, 0, stream>>>(hw, pk, dinv, rowptr, cnt, gcn2_b,
                                                  gidx, h1te);  // -> time_embeds (bf16)

  // attention tail
  k_mm<D, 12, true, 1><<<(MW + 3) / 4, 256, 0, stream>>>(WIb, h1te, in_b, kv, q9b, MW);
  k_attn2<<<(R + 3) / 4, 256, 0, stream>>>(kv, q9b, aob);
  k_mm<D, 4, true, 0><<<(RW + 3) / 4, 256, 0, stream>>>(WOb, aob, nullptr, proj, nullptr, RW);
  k_ln1<<<(R + 3) / 4, 256, 0, stream>>>(h1te, proj, out_b, w1, w2, ln1_g, ln1_b, finf, finb);
  k_mm<D, 4, true, 0><<<(RW + 3) / 4, 256, 0, stream>>>(WFb, finb, nullptr, o2b, nullptr, RW);
  k_ln2<<<(R + 3) / 4, 256, 0, stream>>>(finf, o2b, fc_b, w3, w4, ln2_g, ln2_b, outp);
}